// Round 1
// baseline (29396.802 us; speedup 1.0000x reference)
//
#include <hip/hip_runtime.h>

// Problem constants (DeepCAD_1958505087412)
#define BB   8
#define NN   512      // nodes == timesteps
#define NDIM 128
#define HDIM 256      // GNN out dim == LSTM hidden
#define TT   512

__device__ __forceinline__ float sigmoidf_(float x) { return 1.0f / (1.0f + __expf(-x)); }
__device__ __forceinline__ float tanhf_(float x) { float e = __expf(2.0f * x); return 1.0f - 2.0f / (e + 1.0f); }

// ---------------------------------------------------------------------------
// Y = X @ W^T + bias (optional ReLU). X:(M,K) W:(Nn,K) Y:(M,Nn) row-major.
// 64x64 tile, BK=16, 256 threads, 4x4 per thread. M%64==0, K%16==0 assumed.
// Nn may be < 64 (guarded).
// ---------------------------------------------------------------------------
template<int RELU>
__global__ __launch_bounds__(256) void gemm_nt(const float* __restrict__ X,
    const float* __restrict__ W, const float* __restrict__ bias,
    float* __restrict__ Y, int M, int K, int Nn)
{
    __shared__ float Xs[16][68];
    __shared__ float Ws[16][68];
    const int tid = threadIdx.x;
    const int m0 = blockIdx.y << 6;
    const int n0 = blockIdx.x << 6;
    const int lr = tid >> 2;           // 0..63
    const int lc = (tid & 3) << 2;     // 0,4,8,12
    const int tm = (tid >> 4) << 2;    // 0..60
    const int tn = (tid & 15) << 2;    // 0..60

    float acc[4][4] = {{0.f,0.f,0.f,0.f},{0.f,0.f,0.f,0.f},{0.f,0.f,0.f,0.f},{0.f,0.f,0.f,0.f}};

    const float* Xp = X + (size_t)(m0 + lr) * K + lc;
    const bool wok = (n0 + lr) < Nn;
    const float* Wp = wok ? (W + (size_t)(n0 + lr) * K + lc) : W;

    for (int k0 = 0; k0 < K; k0 += 16) {
        float4 xv = *(const float4*)(Xp + k0);
        float4 wv = *(const float4*)(Wp + k0);
        if (!wok) wv = make_float4(0.f, 0.f, 0.f, 0.f);
        __syncthreads();
        Xs[lc+0][lr]=xv.x; Xs[lc+1][lr]=xv.y; Xs[lc+2][lr]=xv.z; Xs[lc+3][lr]=xv.w;
        Ws[lc+0][lr]=wv.x; Ws[lc+1][lr]=wv.y; Ws[lc+2][lr]=wv.z; Ws[lc+3][lr]=wv.w;
        __syncthreads();
        #pragma unroll
        for (int kk = 0; kk < 16; ++kk) {
            const float4 a = *(const float4*)(&Xs[kk][tm]);
            const float4 b = *(const float4*)(&Ws[kk][tn]);
            acc[0][0] += a.x*b.x; acc[0][1] += a.x*b.y; acc[0][2] += a.x*b.z; acc[0][3] += a.x*b.w;
            acc[1][0] += a.y*b.x; acc[1][1] += a.y*b.y; acc[1][2] += a.y*b.z; acc[1][3] += a.y*b.w;
            acc[2][0] += a.z*b.x; acc[2][1] += a.z*b.y; acc[2][2] += a.z*b.z; acc[2][3] += a.z*b.w;
            acc[3][0] += a.w*b.x; acc[3][1] += a.w*b.y; acc[3][2] += a.w*b.z; acc[3][3] += a.w*b.w;
        }
    }
    const int nc = n0 + tn;
    if (nc >= Nn) return;
    float4 bv = make_float4(0.f, 0.f, 0.f, 0.f);
    if (bias) bv = *(const float4*)(bias + nc);
    #pragma unroll
    for (int i = 0; i < 4; ++i) {
        float4 o;
        o.x = acc[i][0] + bv.x; o.y = acc[i][1] + bv.y;
        o.z = acc[i][2] + bv.z; o.w = acc[i][3] + bv.w;
        if (RELU) { o.x=fmaxf(o.x,0.f); o.y=fmaxf(o.y,0.f); o.z=fmaxf(o.z,0.f); o.w=fmaxf(o.w,0.f); }
        *(float4*)(Y + (size_t)(m0 + tm + i) * Nn + nc) = o;
    }
}

// ---------------------------------------------------------------------------
// Batched Y[b] = (A[b] @ H[b]) * mask[b,:,None], optional ReLU.
// A:(B,M,K) H:(B,K,Nn) Y:(B,M,Nn). M,K %64==0 / %16==0; Nn %64==0.
// ---------------------------------------------------------------------------
template<int RELU>
__global__ __launch_bounds__(256) void gemm_nn_mask(const float* __restrict__ A,
    const float* __restrict__ Hm, const float* __restrict__ mask,
    float* __restrict__ Y, int M, int K, int Nn)
{
    const int b = blockIdx.z;
    A  += (size_t)b * M * K;
    Hm += (size_t)b * K * Nn;
    Y  += (size_t)b * M * Nn;
    __shared__ float As[16][68];
    __shared__ float Hs[16][68];
    const int tid = threadIdx.x;
    const int m0 = blockIdx.y << 6;
    const int n0 = blockIdx.x << 6;
    const int lr = tid >> 2;
    const int lc = (tid & 3) << 2;
    const int hr = tid >> 4;           // 0..15
    const int hc = (tid & 15) << 2;    // 0..60
    const int tm = (tid >> 4) << 2;
    const int tn = (tid & 15) << 2;

    float acc[4][4] = {{0.f,0.f,0.f,0.f},{0.f,0.f,0.f,0.f},{0.f,0.f,0.f,0.f},{0.f,0.f,0.f,0.f}};

    for (int k0 = 0; k0 < K; k0 += 16) {
        float4 av = *(const float4*)(A + (size_t)(m0 + lr) * K + k0 + lc);
        float4 hv = *(const float4*)(Hm + (size_t)(k0 + hr) * Nn + n0 + hc);
        __syncthreads();
        As[lc+0][lr]=av.x; As[lc+1][lr]=av.y; As[lc+2][lr]=av.z; As[lc+3][lr]=av.w;
        *(float4*)(&Hs[hr][hc]) = hv;
        __syncthreads();
        #pragma unroll
        for (int kk = 0; kk < 16; ++kk) {
            const float4 a = *(const float4*)(&As[kk][tm]);
            const float4 h = *(const float4*)(&Hs[kk][tn]);
            acc[0][0] += a.x*h.x; acc[0][1] += a.x*h.y; acc[0][2] += a.x*h.z; acc[0][3] += a.x*h.w;
            acc[1][0] += a.y*h.x; acc[1][1] += a.y*h.y; acc[1][2] += a.y*h.z; acc[1][3] += a.y*h.w;
            acc[2][0] += a.z*h.x; acc[2][1] += a.z*h.y; acc[2][2] += a.z*h.z; acc[2][3] += a.z*h.w;
            acc[3][0] += a.w*h.x; acc[3][1] += a.w*h.y; acc[3][2] += a.w*h.z; acc[3][3] += a.w*h.w;
        }
    }
    #pragma unroll
    for (int i = 0; i < 4; ++i) {
        const float mk = mask[b * M + m0 + tm + i];
        float4 o;
        o.x = acc[i][0]*mk; o.y = acc[i][1]*mk; o.z = acc[i][2]*mk; o.w = acc[i][3]*mk;
        if (RELU) { o.x=fmaxf(o.x,0.f); o.y=fmaxf(o.y,0.f); o.z=fmaxf(o.z,0.f); o.w=fmaxf(o.w,0.f); }
        *(float4*)(Y + (size_t)(m0 + tm + i) * Nn + n0 + tn) = o;
    }
}

// ---------------------------------------------------------------------------
// si[r] = h[r,:] . aw[0:256] + ab ;  sj[r] = h[r,:] . aw[256:512]
// One wave per row (4 rows / 256-thread block).
// ---------------------------------------------------------------------------
__global__ __launch_bounds__(256) void attn_sisj(const float* __restrict__ h,
    const float* __restrict__ aw, const float* __restrict__ ab,
    float* __restrict__ si, float* __restrict__ sj)
{
    const int lane = threadIdx.x & 63;
    const int row  = (blockIdx.x << 2) + (threadIdx.x >> 6);
    const float4 hv = ((const float4*)(h + (size_t)row * HDIM))[lane];
    const float4 a1 = ((const float4*)aw)[lane];
    const float4 a2 = ((const float4*)(aw + HDIM))[lane];
    float s1 = hv.x*a1.x + hv.y*a1.y + hv.z*a1.z + hv.w*a1.w;
    float s2 = hv.x*a2.x + hv.y*a2.y + hv.z*a2.z + hv.w*a2.w;
    #pragma unroll
    for (int off = 32; off > 0; off >>= 1) {
        s1 += __shfl_down(s1, off);
        s2 += __shfl_down(s2, off);
    }
    if (lane == 0) { si[row] = s1 + ab[0]; sj[row] = s2; }
}

// ---------------------------------------------------------------------------
// For row (b,i): s_j = sigmoid(si+sj)*adj*mask_i*mask_j; watt = s / (sum_j s + 1e-8)
// One block per (b,i); 512 threads (one per j).
// ---------------------------------------------------------------------------
__global__ __launch_bounds__(512) void attn_score(const float* __restrict__ si,
    const float* __restrict__ sj, const float* __restrict__ adj,
    const float* __restrict__ mask, float* __restrict__ watt)
{
    const int bi = blockIdx.x;           // b*NN + i
    const int b  = bi >> 9;
    const int j  = threadIdx.x;
    const float s0 = si[bi];
    const float mi = mask[bi];
    float s = sigmoidf_(s0 + sj[(b << 9) + j]) * adj[(size_t)bi * NN + j] * mi * mask[(b << 9) + j];
    float t = s;
    #pragma unroll
    for (int off = 32; off > 0; off >>= 1) t += __shfl_down(t, off);
    __shared__ float red[8];
    const int lane = j & 63, wv = j >> 6;
    if (lane == 0) red[wv] = t;
    __syncthreads();
    if (j == 0) {
        float tot = 0.f;
        #pragma unroll
        for (int w = 0; w < 8; ++w) tot += red[w];
        red[0] = 1.0f / (tot + 1e-8f);
    }
    __syncthreads();
    watt[(size_t)bi * NN + j] = s * red[0];
}

// ---------------------------------------------------------------------------
// LSTM recurrence, both directions in one launch. One block per (batch,dir).
// pre_*: (B,T,1024) precomputed x@Wih^T + b (gates i,f,g,o).
// whh_*: (1024,256). out: (B,T,512) -> fwd in [:,:,0:256], bwd in [:,:,256:512].
// 1024 threads: thread j computes gate j; threads <256 do the pointwise update.
// ---------------------------------------------------------------------------
__global__ __launch_bounds__(1024) void lstm_scan(const float* __restrict__ pre_f,
    const float* __restrict__ pre_b, const float* __restrict__ whh_f,
    const float* __restrict__ whh_b, float* __restrict__ out)
{
    const int batch = blockIdx.x >> 1;
    const int dir   = blockIdx.x & 1;
    const int j = threadIdx.x;
    const float* pre = dir ? pre_b : pre_f;
    const float* whh = dir ? whh_b : whh_f;
    __shared__ float h_s[HDIM];
    __shared__ float g_s[4 * HDIM];
    const float4* wrow = (const float4*)(whh + (size_t)j * HDIM);
    float c = 0.f;
    if (j < HDIM) h_s[j] = 0.f;
    __syncthreads();
    for (int t = 0; t < TT; ++t) {
        const int tt = dir ? (TT - 1 - t) : t;
        float g = pre[((size_t)batch * TT + tt) * 1024 + j];
        const float4* h4 = (const float4*)h_s;
        #pragma unroll 16
        for (int k = 0; k < HDIM / 4; ++k) {
            const float4 w  = wrow[k];
            const float4 hv = h4[k];
            g += w.x * hv.x; g += w.y * hv.y; g += w.z * hv.z; g += w.w * hv.w;
        }
        g_s[j] = g;
        __syncthreads();
        if (j < HDIM) {
            const float ig = sigmoidf_(g_s[j]);
            const float fg = sigmoidf_(g_s[j + HDIM]);
            const float gg = tanhf_(g_s[j + 2 * HDIM]);
            const float og = sigmoidf_(g_s[j + 3 * HDIM]);
            c = fg * c + ig * gg;
            const float hnew = og * tanhf_(c);
            h_s[j] = hnew;
            out[((size_t)batch * TT + tt) * 512 + dir * HDIM + j] = hnew;
        }
        __syncthreads();
    }
}

// ---------------------------------------------------------------------------

extern "C" void kernel_launch(void* const* d_in, const int* in_sizes, int n_in,
                              void* d_out, int out_size, void* d_ws, size_t ws_size,
                              hipStream_t stream)
{
    const float* nf   = (const float*)d_in[0];
    const float* adj  = (const float*)d_in[1];
    const float* mask = (const float*)d_in[2];
    // d_in[3] = op_types (unused; only shape matters in reference)
    const float* g_w[3]  = {(const float*)d_in[4],  (const float*)d_in[8],  (const float*)d_in[12]};
    const float* g_b[3]  = {(const float*)d_in[5],  (const float*)d_in[9],  (const float*)d_in[13]};
    const float* g_aw[3] = {(const float*)d_in[6],  (const float*)d_in[10], (const float*)d_in[14]};
    const float* g_ab[3] = {(const float*)d_in[7],  (const float*)d_in[11], (const float*)d_in[15]};
    const float* wih0f = (const float*)d_in[16]; const float* whh0f = (const float*)d_in[17]; const float* b0f = (const float*)d_in[18];
    const float* wih0b = (const float*)d_in[19]; const float* whh0b = (const float*)d_in[20]; const float* b0b = (const float*)d_in[21];
    const float* wih1f = (const float*)d_in[22]; const float* whh1f = (const float*)d_in[23]; const float* b1f = (const float*)d_in[24];
    const float* wih1b = (const float*)d_in[25]; const float* whh1b = (const float*)d_in[26]; const float* b1b = (const float*)d_in[27];

    float* ws = (float*)d_ws;
    // Workspace layout (floats); total 15,736,832 floats = ~63 MB
    float* bufA = ws;                       // (4096,256)  GNN h projection / head tmp
    float* bufB = bufA + 1048576;           // (4096,256)  GNN layer output
    float* bufC = bufB + 1048576;           // (4096,256)  GNN3 output (kept for nd head)
    float* si   = bufC + 1048576;           // (4096)
    float* sj   = si + 4096;                // (4096)
    float* out0 = sj + 4096;                // (4096,512) LSTM layer0 output
    float* out1 = out0 + 2097152;           // (4096,512) LSTM layer1 output
    float* P0   = out1 + 2097152;           // (4096,1024) pre-activations fwd
    float* P1   = P0 + 4194304;             // (4096,1024) pre-activations bwd
    float* watt = P0;                       // alias: attention weights (GNN phase only), 8 MB

    const int MR = BB * NN;                 // 4096 rows
    dim3 blk(256);

    // ---------------- GNN x3 ----------------
    auto run_gnn = [&](const float* xin, int Kin, int li, float* ob, bool relu) {
        gemm_nt<0><<<dim3(HDIM / 64, MR / 64), blk, 0, stream>>>(xin, g_w[li], g_b[li], bufA, MR, Kin, HDIM);
        attn_sisj<<<dim3(MR / 4), blk, 0, stream>>>(bufA, g_aw[li], g_ab[li], si, sj);
        attn_score<<<dim3(MR), dim3(512), 0, stream>>>(si, sj, adj, mask, watt);
        if (relu)
            gemm_nn_mask<1><<<dim3(HDIM / 64, NN / 64, BB), blk, 0, stream>>>(watt, bufA, mask, ob, NN, NN, HDIM);
        else
            gemm_nn_mask<0><<<dim3(HDIM / 64, NN / 64, BB), blk, 0, stream>>>(watt, bufA, mask, ob, NN, NN, HDIM);
    };
    run_gnn(nf,   NDIM, 0, bufB, true);
    run_gnn(bufB, HDIM, 1, bufB, true);   // out overwrites input only after it is consumed
    run_gnn(bufB, HDIM, 2, bufC, false);

    // ---------------- LSTM layer 0 ----------------
    gemm_nt<0><<<dim3(16, MR / 64), blk, 0, stream>>>(bufC, wih0f, b0f, P0, MR, HDIM, 1024);
    gemm_nt<0><<<dim3(16, MR / 64), blk, 0, stream>>>(bufC, wih0b, b0b, P1, MR, HDIM, 1024);
    lstm_scan<<<dim3(BB * 2), dim3(1024), 0, stream>>>(P0, P1, whh0f, whh0b, out0);

    // ---------------- LSTM layer 1 ----------------
    gemm_nt<0><<<dim3(16, MR / 64), blk, 0, stream>>>(out0, wih1f, b1f, P0, MR, 512, 1024);
    gemm_nt<0><<<dim3(16, MR / 64), blk, 0, stream>>>(out0, wih1b, b1b, P1, MR, 512, 1024);
    lstm_scan<<<dim3(BB * 2), dim3(1024), 0, stream>>>(P0, P1, whh1f, whh1b, out1);

    // ---------------- Heads ----------------
    float* out = (float*)d_out;
    // op: (B,N,64) at offset 0
    gemm_nt<1><<<dim3(4, MR / 64), blk, 0, stream>>>(out1, (const float*)d_in[28], (const float*)d_in[29], bufA, MR, 512, 256);
    gemm_nt<0><<<dim3(1, MR / 64), blk, 0, stream>>>(bufA, (const float*)d_in[30], (const float*)d_in[31], out, MR, 256, 64);
    // pp: (B,N,16) at offset 262144
    gemm_nt<1><<<dim3(4, MR / 64), blk, 0, stream>>>(out1, (const float*)d_in[32], (const float*)d_in[33], bufA, MR, 512, 256);
    gemm_nt<0><<<dim3(1, MR / 64), blk, 0, stream>>>(bufA, (const float*)d_in[34], (const float*)d_in[35], out + 262144, MR, 256, 16);
    // sk: (B,N,128) at offset 327680
    gemm_nt<1><<<dim3(4, MR / 64), blk, 0, stream>>>(out1, (const float*)d_in[36], (const float*)d_in[37], bufA, MR, 512, 256);
    gemm_nt<0><<<dim3(2, MR / 64), blk, 0, stream>>>(bufA, (const float*)d_in[38], (const float*)d_in[39], out + 327680, MR, 256, 128);
    // nd: (B,N,128) at offset 851968 (input = GNN3 output)
    gemm_nt<1><<<dim3(4, MR / 64), blk, 0, stream>>>(bufC, (const float*)d_in[40], (const float*)d_in[41], bufA, MR, 256, 256);
    gemm_nt<0><<<dim3(2, MR / 64), blk, 0, stream>>>(bufA, (const float*)d_in[42], (const float*)d_in[43], out + 851968, MR, 256, 128);
}

// Round 2
// 5135.257 us; speedup vs baseline: 5.7245x; 5.7245x over previous
//
#include <hip/hip_runtime.h>

// Problem constants (DeepCAD_1958505087412)
#define BB   8
#define NN   512      // nodes == timesteps
#define NDIM 128
#define HDIM 256      // GNN out dim == LSTM hidden
#define TT   512

__device__ __forceinline__ float sigmoidf_(float x) { return 1.0f / (1.0f + __expf(-x)); }
__device__ __forceinline__ float tanhf_(float x) { float e = __expf(2.0f * x); return 1.0f - 2.0f / (e + 1.0f); }

// ---------------------------------------------------------------------------
// Y = X @ W^T + bias (optional ReLU). X:(M,K) W:(Nn,K) Y:(M,Nn) row-major.
// 64x64 tile, BK=16, 256 threads, 4x4 per thread. M%64==0, K%16==0 assumed.
// ---------------------------------------------------------------------------
template<int RELU>
__global__ __launch_bounds__(256) void gemm_nt(const float* __restrict__ X,
    const float* __restrict__ W, const float* __restrict__ bias,
    float* __restrict__ Y, int M, int K, int Nn)
{
    __shared__ float Xs[16][68];
    __shared__ float Ws[16][68];
    const int tid = threadIdx.x;
    const int m0 = blockIdx.y << 6;
    const int n0 = blockIdx.x << 6;
    const int lr = tid >> 2;           // 0..63
    const int lc = (tid & 3) << 2;     // 0,4,8,12
    const int tm = (tid >> 4) << 2;    // 0..60
    const int tn = (tid & 15) << 2;    // 0..60

    float acc[4][4] = {{0.f,0.f,0.f,0.f},{0.f,0.f,0.f,0.f},{0.f,0.f,0.f,0.f},{0.f,0.f,0.f,0.f}};

    const float* Xp = X + (size_t)(m0 + lr) * K + lc;
    const bool wok = (n0 + lr) < Nn;
    const float* Wp = wok ? (W + (size_t)(n0 + lr) * K + lc) : W;

    for (int k0 = 0; k0 < K; k0 += 16) {
        float4 xv = *(const float4*)(Xp + k0);
        float4 wv = *(const float4*)(Wp + k0);
        if (!wok) wv = make_float4(0.f, 0.f, 0.f, 0.f);
        __syncthreads();
        Xs[lc+0][lr]=xv.x; Xs[lc+1][lr]=xv.y; Xs[lc+2][lr]=xv.z; Xs[lc+3][lr]=xv.w;
        Ws[lc+0][lr]=wv.x; Ws[lc+1][lr]=wv.y; Ws[lc+2][lr]=wv.z; Ws[lc+3][lr]=wv.w;
        __syncthreads();
        #pragma unroll
        for (int kk = 0; kk < 16; ++kk) {
            const float4 a = *(const float4*)(&Xs[kk][tm]);
            const float4 b = *(const float4*)(&Ws[kk][tn]);
            acc[0][0] += a.x*b.x; acc[0][1] += a.x*b.y; acc[0][2] += a.x*b.z; acc[0][3] += a.x*b.w;
            acc[1][0] += a.y*b.x; acc[1][1] += a.y*b.y; acc[1][2] += a.y*b.z; acc[1][3] += a.y*b.w;
            acc[2][0] += a.z*b.x; acc[2][1] += a.z*b.y; acc[2][2] += a.z*b.z; acc[2][3] += a.z*b.w;
            acc[3][0] += a.w*b.x; acc[3][1] += a.w*b.y; acc[3][2] += a.w*b.z; acc[3][3] += a.w*b.w;
        }
    }
    const int nc = n0 + tn;
    if (nc >= Nn) return;
    float4 bv = make_float4(0.f, 0.f, 0.f, 0.f);
    if (bias) bv = *(const float4*)(bias + nc);
    #pragma unroll
    for (int i = 0; i < 4; ++i) {
        float4 o;
        o.x = acc[i][0] + bv.x; o.y = acc[i][1] + bv.y;
        o.z = acc[i][2] + bv.z; o.w = acc[i][3] + bv.w;
        if (RELU) { o.x=fmaxf(o.x,0.f); o.y=fmaxf(o.y,0.f); o.z=fmaxf(o.z,0.f); o.w=fmaxf(o.w,0.f); }
        *(float4*)(Y + (size_t)(m0 + tm + i) * Nn + nc) = o;
    }
}

// ---------------------------------------------------------------------------
// Batched Y[b] = (A[b] @ H[b]) * mask[b,:,None], optional ReLU.
// ---------------------------------------------------------------------------
template<int RELU>
__global__ __launch_bounds__(256) void gemm_nn_mask(const float* __restrict__ A,
    const float* __restrict__ Hm, const float* __restrict__ mask,
    float* __restrict__ Y, int M, int K, int Nn)
{
    const int b = blockIdx.z;
    A  += (size_t)b * M * K;
    Hm += (size_t)b * K * Nn;
    Y  += (size_t)b * M * Nn;
    __shared__ float As[16][68];
    __shared__ float Hs[16][68];
    const int tid = threadIdx.x;
    const int m0 = blockIdx.y << 6;
    const int n0 = blockIdx.x << 6;
    const int lr = tid >> 2;
    const int lc = (tid & 3) << 2;
    const int hr = tid >> 4;           // 0..15
    const int hc = (tid & 15) << 2;    // 0..60
    const int tm = (tid >> 4) << 2;
    const int tn = (tid & 15) << 2;

    float acc[4][4] = {{0.f,0.f,0.f,0.f},{0.f,0.f,0.f,0.f},{0.f,0.f,0.f,0.f},{0.f,0.f,0.f,0.f}};

    for (int k0 = 0; k0 < K; k0 += 16) {
        float4 av = *(const float4*)(A + (size_t)(m0 + lr) * K + k0 + lc);
        float4 hv = *(const float4*)(Hm + (size_t)(k0 + hr) * Nn + n0 + hc);
        __syncthreads();
        As[lc+0][lr]=av.x; As[lc+1][lr]=av.y; As[lc+2][lr]=av.z; As[lc+3][lr]=av.w;
        *(float4*)(&Hs[hr][hc]) = hv;
        __syncthreads();
        #pragma unroll
        for (int kk = 0; kk < 16; ++kk) {
            const float4 a = *(const float4*)(&As[kk][tm]);
            const float4 h = *(const float4*)(&Hs[kk][tn]);
            acc[0][0] += a.x*h.x; acc[0][1] += a.x*h.y; acc[0][2] += a.x*h.z; acc[0][3] += a.x*h.w;
            acc[1][0] += a.y*h.x; acc[1][1] += a.y*h.y; acc[1][2] += a.y*h.z; acc[1][3] += a.y*h.w;
            acc[2][0] += a.z*h.x; acc[2][1] += a.z*h.y; acc[2][2] += a.z*h.z; acc[2][3] += a.z*h.w;
            acc[3][0] += a.w*h.x; acc[3][1] += a.w*h.y; acc[3][2] += a.w*h.z; acc[3][3] += a.w*h.w;
        }
    }
    #pragma unroll
    for (int i = 0; i < 4; ++i) {
        const float mk = mask[b * M + m0 + tm + i];
        float4 o;
        o.x = acc[i][0]*mk; o.y = acc[i][1]*mk; o.z = acc[i][2]*mk; o.w = acc[i][3]*mk;
        if (RELU) { o.x=fmaxf(o.x,0.f); o.y=fmaxf(o.y,0.f); o.z=fmaxf(o.z,0.f); o.w=fmaxf(o.w,0.f); }
        *(float4*)(Y + (size_t)(m0 + tm + i) * Nn + n0 + tn) = o;
    }
}

// ---------------------------------------------------------------------------
__global__ __launch_bounds__(256) void attn_sisj(const float* __restrict__ h,
    const float* __restrict__ aw, const float* __restrict__ ab,
    float* __restrict__ si, float* __restrict__ sj)
{
    const int lane = threadIdx.x & 63;
    const int row  = (blockIdx.x << 2) + (threadIdx.x >> 6);
    const float4 hv = ((const float4*)(h + (size_t)row * HDIM))[lane];
    const float4 a1 = ((const float4*)aw)[lane];
    const float4 a2 = ((const float4*)(aw + HDIM))[lane];
    float s1 = hv.x*a1.x + hv.y*a1.y + hv.z*a1.z + hv.w*a1.w;
    float s2 = hv.x*a2.x + hv.y*a2.y + hv.z*a2.z + hv.w*a2.w;
    #pragma unroll
    for (int off = 32; off > 0; off >>= 1) {
        s1 += __shfl_down(s1, off);
        s2 += __shfl_down(s2, off);
    }
    if (lane == 0) { si[row] = s1 + ab[0]; sj[row] = s2; }
}

// ---------------------------------------------------------------------------
__global__ __launch_bounds__(512) void attn_score(const float* __restrict__ si,
    const float* __restrict__ sj, const float* __restrict__ adj,
    const float* __restrict__ mask, float* __restrict__ watt)
{
    const int bi = blockIdx.x;           // b*NN + i
    const int b  = bi >> 9;
    const int j  = threadIdx.x;
    const float s0 = si[bi];
    const float mi = mask[bi];
    float s = sigmoidf_(s0 + sj[(b << 9) + j]) * adj[(size_t)bi * NN + j] * mi * mask[(b << 9) + j];
    float t = s;
    #pragma unroll
    for (int off = 32; off > 0; off >>= 1) t += __shfl_down(t, off);
    __shared__ float red[8];
    const int lane = j & 63, wv = j >> 6;
    if (lane == 0) red[wv] = t;
    __syncthreads();
    if (j == 0) {
        float tot = 0.f;
        #pragma unroll
        for (int w = 0; w < 8; ++w) tot += red[w];
        red[0] = 1.0f / (tot + 1e-8f);
    }
    __syncthreads();
    watt[(size_t)bi * NN + j] = s * red[0];
}

// ---------------------------------------------------------------------------
// Small zero-init for the cooperative-scan h buffer + flags.
// ---------------------------------------------------------------------------
__global__ __launch_bounds__(256) void zero_ws(float* __restrict__ p, int n)
{
    for (int i = threadIdx.x + blockIdx.x * 256; i < n; i += 256 * gridDim.x) p[i] = 0.f;
}

// ---------------------------------------------------------------------------
// Cooperative multi-block LSTM scan (both directions, all batches).
// Grid: 128 blocks = 16 chains (batch*2+dir) x 8 slices. Block: 256 threads.
// Each block owns 32 hidden units (=128 gate rows) of one chain. Weights are
// register-stationary (128 floats/thread). Per step, h (256 floats/chain) is
// exchanged through a double-buffered global buffer with device-scope atomics
// and a per-slice monotonic step flag.
//   hb: float[2][16][256] (zeroed)   fl: int[16][8] (zeroed)
//   pre_*: (B,T,1024) = x@Wih^T + b  (gates i,f,g,o)
//   out: (B,T,512), fwd->[0:256], bwd->[256:512], aligned with input positions
// ---------------------------------------------------------------------------
__global__ __launch_bounds__(256, 1) void lstm_scan2(const float* __restrict__ pre_f,
    const float* __restrict__ pre_b, const float* __restrict__ whh_f,
    const float* __restrict__ whh_b, float* __restrict__ out,
    float* __restrict__ hb, int* __restrict__ fl)
{
    const int chain = blockIdx.x >> 3;   // 0..15
    const int slice = blockIdx.x & 7;    // 0..7
    const int batch = chain >> 1;
    const int dir   = chain & 1;
    const float* pre = dir ? pre_b : pre_f;
    const float* whh = dir ? whh_b : whh_f;

    const int t0    = threadIdx.x;
    const int lr    = t0 >> 1;           // 0..127 local gate row
    const int khalf = t0 & 1;            // which K half this thread dots
    const int gate  = lr >> 5;           // 0..3 = i,f,g,o
    const int j     = lr & 31;           // hidden offset within slice
    const int grow  = gate * 256 + slice * 32 + j;   // row in whh (1024x256)

    // ---- weights -> registers (one-time), 128 floats/thread ----
    float wreg[128];
    const float4* wp = (const float4*)(whh + (size_t)grow * 256 + khalf * 128);
    #pragma unroll
    for (int q = 0; q < 32; ++q) {
        const float4 v = wp[q];
        wreg[4*q+0] = v.x; wreg[4*q+1] = v.y; wreg[4*q+2] = v.z; wreg[4*q+3] = v.w;
    }

    __shared__ float h_s[256];
    __shared__ float g_s[128];
    float c = 0.f;
    int* myflags = fl + chain * 8;
    float* hb_chain = hb + chain * 256;

    for (int t = 0; t < TT; ++t) {
        const int tt = dir ? (TT - 1 - t) : t;

        // ---- wait until all 8 slices of this chain published h_t ----
        if (t > 0) {
            if (t0 < 8) {
                while (__hip_atomic_load(&myflags[t0], __ATOMIC_ACQUIRE,
                                         __HIP_MEMORY_SCOPE_AGENT) < t) { }
            }
            __syncthreads();
        }

        // ---- read h_t from the coherent double buffer ----
        h_s[t0] = __hip_atomic_load(&hb_chain[(size_t)(t & 1) * 4096 + t0],
                                    __ATOMIC_RELAXED, __HIP_MEMORY_SCOPE_AGENT);
        __syncthreads();

        // ---- matvec: g[grow] = pre + sum_k whh[grow][k]*h[k] ----
        float pv = 0.f;
        if (khalf == 0) pv = pre[((size_t)batch * TT + tt) * 1024 + grow];
        float g = 0.f;
        const float4* h4 = ((const float4*)h_s) + khalf * 32;
        #pragma unroll
        for (int q = 0; q < 32; ++q) {
            const float4 hv = h4[q];
            g += wreg[4*q+0]*hv.x + wreg[4*q+1]*hv.y + wreg[4*q+2]*hv.z + wreg[4*q+3]*hv.w;
        }
        g += __shfl_xor(g, 1);           // combine the two K-halves
        if (khalf == 0) g_s[lr] = g + pv;
        __syncthreads();

        // ---- pointwise update for this block's 32 hidden units ----
        if (t0 < 32) {
            const float ig = sigmoidf_(g_s[t0]);
            const float fg = sigmoidf_(g_s[32 + t0]);
            const float gg = tanhf_(g_s[64 + t0]);
            const float og = sigmoidf_(g_s[96 + t0]);
            c = fg * c + ig * gg;
            const float hnew = og * tanhf_(c);
            const int hcol = slice * 32 + t0;
            __hip_atomic_store(&hb_chain[(size_t)((t + 1) & 1) * 4096 + hcol], hnew,
                               __ATOMIC_RELAXED, __HIP_MEMORY_SCOPE_AGENT);
            out[((size_t)batch * TT + tt) * 512 + dir * 256 + hcol] = hnew;
        }
        __syncthreads();                 // drains vmcnt: h stores visible device-wide

        if (t0 == 0)
            __hip_atomic_store(&myflags[slice], t + 1, __ATOMIC_RELEASE,
                               __HIP_MEMORY_SCOPE_AGENT);
    }
}

// ---------------------------------------------------------------------------

extern "C" void kernel_launch(void* const* d_in, const int* in_sizes, int n_in,
                              void* d_out, int out_size, void* d_ws, size_t ws_size,
                              hipStream_t stream)
{
    const float* nf   = (const float*)d_in[0];
    const float* adj  = (const float*)d_in[1];
    const float* mask = (const float*)d_in[2];
    const float* g_w[3]  = {(const float*)d_in[4],  (const float*)d_in[8],  (const float*)d_in[12]};
    const float* g_b[3]  = {(const float*)d_in[5],  (const float*)d_in[9],  (const float*)d_in[13]};
    const float* g_aw[3] = {(const float*)d_in[6],  (const float*)d_in[10], (const float*)d_in[14]};
    const float* g_ab[3] = {(const float*)d_in[7],  (const float*)d_in[11], (const float*)d_in[15]};
    const float* wih0f = (const float*)d_in[16]; const float* whh0f = (const float*)d_in[17]; const float* b0f = (const float*)d_in[18];
    const float* wih0b = (const float*)d_in[19]; const float* whh0b = (const float*)d_in[20]; const float* b0b = (const float*)d_in[21];
    const float* wih1f = (const float*)d_in[22]; const float* whh1f = (const float*)d_in[23]; const float* b1f = (const float*)d_in[24];
    const float* wih1b = (const float*)d_in[25]; const float* whh1b = (const float*)d_in[26]; const float* b1b = (const float*)d_in[27];

    float* ws = (float*)d_ws;
    // Workspace layout (floats); total ~15.7M floats = ~63 MB
    float* bufA = ws;                       // (4096,256)  GNN h projection / head tmp / sync scratch
    float* bufB = bufA + 1048576;           // (4096,256)  GNN layer output
    float* bufC = bufB + 1048576;           // (4096,256)  GNN3 output (kept for nd head)
    float* si   = bufC + 1048576;           // (4096)
    float* sj   = si + 4096;                // (4096)
    float* out0 = sj + 4096;                // (4096,512) LSTM layer0 output
    float* out1 = out0 + 2097152;           // (4096,512) LSTM layer1 output
    float* P0   = out1 + 2097152;           // (4096,1024) pre-activations fwd
    float* P1   = P0 + 4194304;             // (4096,1024) pre-activations bwd
    float* watt = P0;                       // alias: attention weights (GNN phase only)
    // scan sync state aliased onto bufA (free during the LSTM phase):
    float* hb = bufA;                       // [2][16][256] = 8192 floats
    int*   fl = (int*)(bufA + 8192);        // [16][8] = 128 ints
    const int SYNC_FLOATS = 8192 + 128;

    const int MR = BB * NN;                 // 4096 rows
    dim3 blk(256);

    // ---------------- GNN x3 ----------------
    auto run_gnn = [&](const float* xin, int Kin, int li, float* ob, bool relu) {
        gemm_nt<0><<<dim3(HDIM / 64, MR / 64), blk, 0, stream>>>(xin, g_w[li], g_b[li], bufA, MR, Kin, HDIM);
        attn_sisj<<<dim3(MR / 4), blk, 0, stream>>>(bufA, g_aw[li], g_ab[li], si, sj);
        attn_score<<<dim3(MR), dim3(512), 0, stream>>>(si, sj, adj, mask, watt);
        if (relu)
            gemm_nn_mask<1><<<dim3(HDIM / 64, NN / 64, BB), blk, 0, stream>>>(watt, bufA, mask, ob, NN, NN, HDIM);
        else
            gemm_nn_mask<0><<<dim3(HDIM / 64, NN / 64, BB), blk, 0, stream>>>(watt, bufA, mask, ob, NN, NN, HDIM);
    };
    run_gnn(nf,   NDIM, 0, bufB, true);
    run_gnn(bufB, HDIM, 1, bufB, true);
    run_gnn(bufB, HDIM, 2, bufC, false);

    // ---------------- LSTM layer 0 ----------------
    gemm_nt<0><<<dim3(16, MR / 64), blk, 0, stream>>>(bufC, wih0f, b0f, P0, MR, HDIM, 1024);
    gemm_nt<0><<<dim3(16, MR / 64), blk, 0, stream>>>(bufC, wih0b, b0b, P1, MR, HDIM, 1024);
    zero_ws<<<dim3(8), blk, 0, stream>>>(bufA, SYNC_FLOATS);
    lstm_scan2<<<dim3(128), blk, 0, stream>>>(P0, P1, whh0f, whh0b, out0, hb, fl);

    // ---------------- LSTM layer 1 ----------------
    gemm_nt<0><<<dim3(16, MR / 64), blk, 0, stream>>>(out0, wih1f, b1f, P0, MR, 512, 1024);
    gemm_nt<0><<<dim3(16, MR / 64), blk, 0, stream>>>(out0, wih1b, b1b, P1, MR, 512, 1024);
    zero_ws<<<dim3(8), blk, 0, stream>>>(bufA, SYNC_FLOATS);
    lstm_scan2<<<dim3(128), blk, 0, stream>>>(P0, P1, whh1f, whh1b, out1, hb, fl);

    // ---------------- Heads ----------------
    float* out = (float*)d_out;
    // op: (B,N,64) at offset 0
    gemm_nt<1><<<dim3(4, MR / 64), blk, 0, stream>>>(out1, (const float*)d_in[28], (const float*)d_in[29], bufA, MR, 512, 256);
    gemm_nt<0><<<dim3(1, MR / 64), blk, 0, stream>>>(bufA, (const float*)d_in[30], (const float*)d_in[31], out, MR, 256, 64);
    // pp: (B,N,16) at offset 262144
    gemm_nt<1><<<dim3(4, MR / 64), blk, 0, stream>>>(out1, (const float*)d_in[32], (const float*)d_in[33], bufA, MR, 512, 256);
    gemm_nt<0><<<dim3(1, MR / 64), blk, 0, stream>>>(bufA, (const float*)d_in[34], (const float*)d_in[35], out + 262144, MR, 256, 16);
    // sk: (B,N,128) at offset 327680
    gemm_nt<1><<<dim3(4, MR / 64), blk, 0, stream>>>(out1, (const float*)d_in[36], (const float*)d_in[37], bufA, MR, 512, 256);
    gemm_nt<0><<<dim3(2, MR / 64), blk, 0, stream>>>(bufA, (const float*)d_in[38], (const float*)d_in[39], out + 327680, MR, 256, 128);
    // nd: (B,N,128) at offset 851968 (input = GNN3 output)
    gemm_nt<1><<<dim3(4, MR / 64), blk, 0, stream>>>(bufC, (const float*)d_in[40], (const float*)d_in[41], bufA, MR, 256, 256);
    gemm_nt<0><<<dim3(2, MR / 64), blk, 0, stream>>>(bufA, (const float*)d_in[42], (const float*)d_in[43], out + 851968, MR, 256, 128);
}